// Round 11
// baseline (318.717 us; speedup 1.0000x reference)
//
#include <hip/hip_runtime.h>

// Problem constants (from setup_inputs)
#define BB   16      // batches
#define NA   2048    // anchor rows per batch
#define NP   2048    // positive rows per batch
#define DD   512     // feature dim
#define KSEL 32      // selected indices per batch
#define TR   64      // tile rows per match block
#define NT   (NP/TR) // 32 tiles per (batch, matrix)
#define DC   32      // d-chunk (floats) staged per iteration
#define NCH  (DD/DC) // 16 chunks

// Workspace layout (in floats)
#define QT_OFF   0
#define QT_SZ    (BB*DD*KSEL)        // 262144 floats: Qt[b][d][k], normalized, transposed
#define PMAX_OFF (QT_OFF + QT_SZ)
#define PRED_SZ  (BB*2*NT*KSEL)      // 32768 per array
#define PIDX_OFF (PMAX_OFF + PRED_SZ)

__device__ __forceinline__ void gload_lds16(const void* g, void* l) {
  __builtin_amdgcn_global_load_lds(
      (const __attribute__((address_space(1))) unsigned int*)g,
      (__attribute__((address_space(3))) unsigned int*)l,
      16, 0, 0);
}

// ---------------------------------------------------------------------------
// Kernel A: gather + normalize selected anchor rows.
//   - idx_a rows -> A_s output (coalesced)
//   - idx_p rows -> Qt workspace, transposed [b][d][k]
// ---------------------------------------------------------------------------
__global__ __launch_bounds__(256) void prep_kernel(
    const float* __restrict__ anchor, const int* __restrict__ idx_a,
    const int* __restrict__ idx_p, float* __restrict__ outA,
    float* __restrict__ qt_ws) {
  const int blk = blockIdx.x;          // b*32 + k
  const int b = blk >> 5, k = blk & 31;
  const int t = threadIdx.x;
  const int ia = idx_a[blk];
  const int ip = idx_p[blk];
  const float* rowA = anchor + ((size_t)(b*NA + ia))*DD;
  const float* rowP = anchor + ((size_t)(b*NA + ip))*DD;

  float2 a2 = *(const float2*)(rowA + 2*t);
  float2 p2 = *(const float2*)(rowP + 2*t);
  float sa = a2.x*a2.x + a2.y*a2.y;
  float sp = p2.x*p2.x + p2.y*p2.y;
  #pragma unroll
  for (int o = 1; o < 64; o <<= 1) {
    sa += __shfl_xor(sa, o, 64);
    sp += __shfl_xor(sp, o, 64);
  }
  __shared__ float lb[8];
  const int w = t >> 6, l = t & 63;
  if (l == 0) { lb[w] = sa; lb[4+w] = sp; }
  __syncthreads();
  sa = lb[0]+lb[1]+lb[2]+lb[3];
  sp = lb[4]+lb[5]+lb[6]+lb[7];
  const float ra = 1.f / fmaxf(sqrtf(sa), 1e-12f);
  const float rp = 1.f / fmaxf(sqrtf(sp), 1e-12f);

  float2 o2; o2.x = a2.x*ra; o2.y = a2.y*ra;
  *(float2*)(outA + (size_t)blk*DD + 2*t) = o2;

  const int d = 2*t;
  qt_ws[((size_t)b*DD + d  )*KSEL + k] = p2.x*rp;
  qt_ws[((size_t)b*DD + d+1)*KSEL + k] = p2.y*rp;
}

// ---------------------------------------------------------------------------
// Kernel B (occupancy redesign): 1024 blocks (TR=64 rows each), 24KiB LDS ->
// 4 blocks/CU = 4 waves/SIMD. Thread = (qg 8q, ds 8d-slice, rg 4rows);
// d-split reduced by shfl_xor butterfly over lane bits 2-3 at the end.
// Both LDS tiles quad-swizzled (bijective within each row) so every read
// instruction is <=2-way bank aliased (free); inverse permutation applied to
// the global_load_lds SOURCE (linear LDS dest, rule 21).
// ---------------------------------------------------------------------------
__global__ __launch_bounds__(256, 4) void match_kernel(
    const float* __restrict__ p1, const float* __restrict__ p2,
    const float* __restrict__ qt_ws, float* __restrict__ pmax_ws,
    int* __restrict__ pidx_ws) {
  __shared__ float Qc[2][DC*KSEL];   // [dloc][q] quad-swizzled, 2 x 4KB
  __shared__ float Ps[2][TR*DC];     // [r][dloc] quad-swizzled, 2 x 8KB

  const int tile = blockIdx.x, mat = blockIdx.y, b = blockIdx.z;
  const float* __restrict__ P =
      (mat ? p2 : p1) + (size_t)b*NP*DD + (size_t)tile*TR*DD;
  const float* __restrict__ Qsrc = qt_ws + (size_t)b*DD*KSEL;
  const int t = threadIdx.x;
  const int w = t >> 6, l = t & 63;
  const int qg  = l & 3;         // query group (8 q)
  const int ds  = (l >> 2) & 3;  // d-slice (8 of 32 chunk dims)
  const int rgl = l >> 4;        // row group low (4 rows)
  const int rg  = w*4 + rgl;     // row group in [0,16)

  // ---- staging index precompute ----
  // P stage: sid = j*256+t in [0,512); LDS float off = sid*4 (linear).
  //   row r = sid>>3, quad s = sid&7; ds' = ((s>>1) ^ ((r>>2)&3))&3,
  //   dh' = (s&1) ^ ((r>>2)&1); global col = ds'*8 + dh'*4.
  int p_srcoff[2];
  #pragma unroll
  for (int j = 0; j < 2; ++j) {
    const int sid = j*256 + t;
    const int r = sid >> 3, s = sid & 7;
    const int dsd = ((s >> 1) ^ ((r >> 2) & 3)) & 3;
    const int dhd = (s & 1) ^ ((r >> 2) & 1);
    p_srcoff[j] = r*DD + dsd*8 + dhd*4;   // + c*DC at use
  }
  // Q stage: sid = t; LDS float off = t*4 (linear).
  //   dloc = t>>3, quad s = t&7; ds' = dloc>>3; qg' = ((s>>1)^ds')&3,
  //   qh' = (s&1)^(ds'&1); global col = qg'*8 + qh'*4.
  int q_srcoff;
  {
    const int dloc = t >> 3, s = t & 7;
    const int dsd = dloc >> 3;
    const int qgd = ((s >> 1) ^ dsd) & 3;
    const int qhd = (s & 1) ^ (dsd & 1);
    q_srcoff = dloc*KSEL + qgd*8 + qhd*4; // + c*DC*KSEL at use
  }

  // ---- read index precompute ----
  // P read (row r = w*16+rgl*4+i, d-half dh): float off = r*32 + Qp(dh)*4,
  //   Qp(dh) = ((ds^rgl)&3)*2 + (dh ^ (rgl&1)).
  const int pc2 = ((ds ^ rgl) & 3) * 2;
  const int pQ0 = pc2 + ((rgl & 1));        // dh=0
  const int pQ1 = pc2 + (1 ^ (rgl & 1));    // dh=1
  const int pRowBase = (w*16 + rgl*4) * DC; // +i*32, + quad*4
  // Q read (dloc = ds*8+dh*4+dd2, q-half qh): off = dloc*32 + Qq(qh)*4,
  //   Qq(qh) = ((qg^ds)&3)*2 + (qh ^ (ds&1)).
  const int qc2 = ((qg ^ ds) & 3) * 2;
  const int qQ0 = qc2 + ((ds & 1));         // qh=0 -> q = qg*8..+4
  const int qQ1 = qc2 + (1 ^ (ds & 1));     // qh=1 -> q = qg*8+4..+8
  const int qRowBase = ds*8*KSEL;           // +(dh*4+dd2)*32, + quad*4

  // ---- prologue: stage chunk 0 ----
  {
    float* pb = &Ps[0][0];
    gload_lds16(P + p_srcoff[0],           pb + t*4);
    gload_lds16(P + p_srcoff[1],           pb + (256 + t)*4);
    gload_lds16(Qsrc + q_srcoff,           &Qc[0][0] + t*4);
  }
  asm volatile("s_waitcnt vmcnt(0)" ::: "memory");
  __syncthreads();

  float acc[8][4];
  float ssq[4];
  #pragma unroll
  for (int jj = 0; jj < 8; ++jj)
    #pragma unroll
    for (int i = 0; i < 4; ++i) acc[jj][i] = 0.f;
  #pragma unroll
  for (int i = 0; i < 4; ++i) ssq[i] = 0.f;

  #pragma unroll 2
  for (int c = 0; c < NCH; ++c) {
    const int cur = c & 1;
    if (c + 1 < NCH) {
      float* pb = &Ps[cur ^ 1][0];
      const int gc = (c + 1) * DC;
      gload_lds16(P + (size_t)gc + p_srcoff[0], pb + t*4);
      gload_lds16(P + (size_t)gc + p_srcoff[1], pb + (256 + t)*4);
      gload_lds16(Qsrc + (size_t)gc*KSEL + q_srcoff, &Qc[cur ^ 1][0] + t*4);
    }
    const float* __restrict__ pb = &Ps[cur][0];
    const float* __restrict__ qb = &Qc[cur][0];
    #pragma unroll
    for (int dh = 0; dh < 2; ++dh) {
      const int pQ = dh ? pQ1 : pQ0;
      float4 p4[4];
      #pragma unroll
      for (int i = 0; i < 4; ++i)
        p4[i] = *(const float4*)&pb[pRowBase + i*DC + pQ*4];
      #pragma unroll
      for (int dd2 = 0; dd2 < 4; ++dd2) {
        const int drow = qRowBase + (dh*4 + dd2)*KSEL;
        const float4 q0 = *(const float4*)&qb[drow + qQ0*4];
        const float4 q1 = *(const float4*)&qb[drow + qQ1*4];
        #pragma unroll
        for (int i = 0; i < 4; ++i) {
          const float p = (dd2 == 0) ? p4[i].x : (dd2 == 1) ? p4[i].y
                         : (dd2 == 2) ? p4[i].z : p4[i].w;
          acc[0][i] += q0.x*p; acc[1][i] += q0.y*p;
          acc[2][i] += q0.z*p; acc[3][i] += q0.w*p;
          acc[4][i] += q1.x*p; acc[5][i] += q1.y*p;
          acc[6][i] += q1.z*p; acc[7][i] += q1.w*p;
          ssq[i] += p*p;
        }
      }
    }
    asm volatile("s_waitcnt vmcnt(0)" ::: "memory");
    __syncthreads();
  }

  // ---- reduce the 4-way d-split (ds = lane bits 2-3) by butterfly ----
  #pragma unroll
  for (int jj = 0; jj < 8; ++jj)
    #pragma unroll
    for (int i = 0; i < 4; ++i) {
      acc[jj][i] += __shfl_xor(acc[jj][i], 4, 64);
      acc[jj][i] += __shfl_xor(acc[jj][i], 8, 64);
    }
  #pragma unroll
  for (int i = 0; i < 4; ++i) {
    ssq[i] += __shfl_xor(ssq[i], 4, 64);
    ssq[i] += __shfl_xor(ssq[i], 8, 64);
  }

  float rinvp[4];
  #pragma unroll
  for (int i = 0; i < 4; ++i)
    rinvp[i] = 1.f / fmaxf(sqrtf(ssq[i]), 1e-12f);

  // ---- (max, argmax) epilogue; first-occurrence ties (ascending rows) ----
  float* redv = &Ps[0][0];            // [16][32]
  int*   redi = (int*)&Ps[0][512];    // [16][32]

  if (ds == 0) {
    #pragma unroll
    for (int jj = 0; jj < 8; ++jj) {
      const int q = qg*8 + jj;
      float best = -1e30f; int bi = 0;
      #pragma unroll
      for (int i = 0; i < 4; ++i) {
        const float s = acc[jj][i] * rinvp[i];
        if (s > best) { best = s; bi = rg*4 + i; }
      }
      redv[rg*32 + q] = best;
      redi[rg*32 + q] = bi;
    }
  }
  __syncthreads();
  if (t < 32) {
    const int q = t;
    float best = -1e30f; int bi = 0;
    #pragma unroll
    for (int g = 0; g < 16; ++g) {
      const float v = redv[g*32 + q];
      if (v > best) { best = v; bi = redi[g*32 + q]; }
    }
    const int o = ((b*2 + mat)*NT + tile)*KSEL + q;
    pmax_ws[o] = best;
    pidx_ws[o] = tile*TR + bi;
  }
}

// ---------------------------------------------------------------------------
// Kernel C: per (b,k) reduce tile partials, gather+normalize matched rows,
// fuse with weights, renormalize, write P_s.
// ---------------------------------------------------------------------------
__global__ __launch_bounds__(256) void fuse_kernel(
    const float* __restrict__ p1, const float* __restrict__ p2,
    const float* __restrict__ pmax_ws, const int* __restrict__ pidx_ws,
    float* __restrict__ outP) {
  const int blk = blockIdx.x;          // b*32 + k
  const int b = blk >> 5, k = blk & 31;
  const int t = threadIdx.x;

  float w1 = -1e30f, w2 = -1e30f; int i1 = 0, i2 = 0;
  for (int tl = 0; tl < NT; ++tl) {
    const int o1 = ((b*2 + 0)*NT + tl)*KSEL + k;
    const float v = pmax_ws[o1];
    if (v > w1) { w1 = v; i1 = pidx_ws[o1]; }
    const int o2 = ((b*2 + 1)*NT + tl)*KSEL + k;
    const float u = pmax_ws[o2];
    if (u > w2) { w2 = u; i2 = pidx_ws[o2]; }
  }

  const float* r1 = p1 + ((size_t)b*NP + i1)*DD;
  const float* r2 = p2 + ((size_t)b*NP + i2)*DD;
  float2 a  = *(const float2*)(r1 + 2*t);
  float2 c2 = *(const float2*)(r2 + 2*t);
  float s1 = a.x*a.x + a.y*a.y;
  float s2 = c2.x*c2.x + c2.y*c2.y;
  #pragma unroll
  for (int o = 1; o < 64; o <<= 1) {
    s1 += __shfl_xor(s1, o, 64);
    s2 += __shfl_xor(s2, o, 64);
  }
  __shared__ float lb[12];
  const int w = t >> 6, l = t & 63;
  if (l == 0) { lb[w] = s1; lb[4+w] = s2; }
  __syncthreads();
  s1 = lb[0]+lb[1]+lb[2]+lb[3];
  s2 = lb[4]+lb[5]+lb[6]+lb[7];
  const float rn1 = 1.f / fmaxf(sqrtf(s1), 1e-12f);
  const float rn2 = 1.f / fmaxf(sqrtf(s2), 1e-12f);

  const float invd = 1.f / (w1 + w2 + 1e-6f);
  const float fx = (w1*(a.x*rn1)  + w2*(c2.x*rn2)) * invd;
  const float fy = (w1*(a.y*rn1)  + w2*(c2.y*rn2)) * invd;

  float sf = fx*fx + fy*fy;
  #pragma unroll
  for (int o = 1; o < 64; o <<= 1) sf += __shfl_xor(sf, o, 64);
  if (l == 0) lb[8+w] = sf;
  __syncthreads();
  sf = lb[8]+lb[9]+lb[10]+lb[11];
  const float rf = 1.f / fmaxf(sqrtf(sf), 1e-12f);

  float2 o2; o2.x = fx*rf; o2.y = fy*rf;
  *(float2*)(outP + (size_t)blk*DD + 2*t) = o2;
}

extern "C" void kernel_launch(void* const* d_in, const int* in_sizes, int n_in,
                              void* d_out, int out_size, void* d_ws, size_t ws_size,
                              hipStream_t stream) {
  (void)in_sizes; (void)n_in; (void)out_size; (void)ws_size;
  const float* anchor = (const float*)d_in[0];
  const float* p1     = (const float*)d_in[1];
  const float* p2     = (const float*)d_in[2];
  const int*   idx_a  = (const int*)d_in[3];
  const int*   idx_p  = (const int*)d_in[4];

  float* out  = (float*)d_out;
  float* outA = out;                       // (B,K,D)
  float* outP = out + (size_t)BB*KSEL*DD;  // (B,K,D)

  float* ws   = (float*)d_ws;
  float* qt   = ws + QT_OFF;
  float* pmax = ws + PMAX_OFF;
  int*   pidx = (int*)(ws + PIDX_OFF);

  hipLaunchKernelGGL(prep_kernel, dim3(BB*KSEL), dim3(256), 0, stream,
                     anchor, idx_a, idx_p, outA, qt);
  hipLaunchKernelGGL(match_kernel, dim3(NT, 2, BB), dim3(256), 0, stream,
                     p1, p2, qt, pmax, pidx);
  hipLaunchKernelGGL(fuse_kernel, dim3(BB*KSEL), dim3(256), 0, stream,
                     p1, p2, pmax, pidx, outP);
}

// Round 12
// 227.669 us; speedup vs baseline: 1.3999x; 1.3999x over previous
//
#include <hip/hip_runtime.h>

// Problem constants (from setup_inputs)
#define BB   16      // batches
#define NA   2048    // anchor rows per batch
#define NP   2048    // positive rows per batch
#define DD   512     // feature dim
#define KSEL 32      // selected indices per batch
#define TR   64      // tile rows per match block
#define NT   (NP/TR) // 32 tiles per (batch, matrix)
#define DC   32      // d-chunk (floats) staged per iteration
#define NCH  (DD/DC) // 16 chunks

// Workspace layout (in floats)
#define QT_OFF   0
#define QT_SZ    (BB*DD*KSEL)        // 262144 floats: Qt[b][d][k], normalized, transposed
#define PMAX_OFF (QT_OFF + QT_SZ)
#define PRED_SZ  (BB*2*NT*KSEL)      // 32768 per array
#define PIDX_OFF (PMAX_OFF + PRED_SZ)

__device__ __forceinline__ void gload_lds16(const void* g, void* l) {
  __builtin_amdgcn_global_load_lds(
      (const __attribute__((address_space(1))) unsigned int*)g,
      (__attribute__((address_space(3))) unsigned int*)l,
      16, 0, 0);
}

// ---------------------------------------------------------------------------
// Kernel A: gather + normalize selected anchor rows.
//   - idx_a rows -> A_s output (coalesced)
//   - idx_p rows -> Qt workspace, transposed [b][d][k]
// ---------------------------------------------------------------------------
__global__ __launch_bounds__(256) void prep_kernel(
    const float* __restrict__ anchor, const int* __restrict__ idx_a,
    const int* __restrict__ idx_p, float* __restrict__ outA,
    float* __restrict__ qt_ws) {
  const int blk = blockIdx.x;          // b*32 + k
  const int b = blk >> 5, k = blk & 31;
  const int t = threadIdx.x;
  const int ia = idx_a[blk];
  const int ip = idx_p[blk];
  const float* rowA = anchor + ((size_t)(b*NA + ia))*DD;
  const float* rowP = anchor + ((size_t)(b*NA + ip))*DD;

  float2 a2 = *(const float2*)(rowA + 2*t);
  float2 p2 = *(const float2*)(rowP + 2*t);
  float sa = a2.x*a2.x + a2.y*a2.y;
  float sp = p2.x*p2.x + p2.y*p2.y;
  #pragma unroll
  for (int o = 1; o < 64; o <<= 1) {
    sa += __shfl_xor(sa, o, 64);
    sp += __shfl_xor(sp, o, 64);
  }
  __shared__ float lb[8];
  const int w = t >> 6, l = t & 63;
  if (l == 0) { lb[w] = sa; lb[4+w] = sp; }
  __syncthreads();
  sa = lb[0]+lb[1]+lb[2]+lb[3];
  sp = lb[4]+lb[5]+lb[6]+lb[7];
  const float ra = 1.f / fmaxf(sqrtf(sa), 1e-12f);
  const float rp = 1.f / fmaxf(sqrtf(sp), 1e-12f);

  float2 o2; o2.x = a2.x*ra; o2.y = a2.y*ra;
  *(float2*)(outA + (size_t)blk*DD + 2*t) = o2;

  const int d = 2*t;
  qt_ws[((size_t)b*DD + d  )*KSEL + k] = p2.x*rp;
  qt_ws[((size_t)b*DD + d+1)*KSEL + k] = p2.y*rp;
}

// ---------------------------------------------------------------------------
// Kernel B: 1024 blocks (TR=64 rows), 24KiB LDS. Thread = (qg 8q, ds 8d-slice,
// rg 4rows); d-split reduced by shfl_xor butterfly at the end.
// LDS tiles quad-swizzled (bijective per row); inverse permutation applied to
// the global_load_lds SOURCE (linear LDS dest, rule 21).
// NOTE (R11 post-mortem): __launch_bounds__(256,4) capped VGPRs at 64 ->
// ~40 regs spilled -> 233MB scratch writes/dispatch -> 163us (2.2x WORSE).
// No min-waves arg: compiler allocates ~90-110 VGPRs (<=128 still gives
// 4 waves/SIMD per the 64/128/256 occupancy steps) with ZERO spill.
// ---------------------------------------------------------------------------
__global__ __launch_bounds__(256) void match_kernel(
    const float* __restrict__ p1, const float* __restrict__ p2,
    const float* __restrict__ qt_ws, float* __restrict__ pmax_ws,
    int* __restrict__ pidx_ws) {
  __shared__ float Qc[2][DC*KSEL];   // [dloc][q] quad-swizzled, 2 x 4KB
  __shared__ float Ps[2][TR*DC];     // [r][dloc] quad-swizzled, 2 x 8KB

  const int tile = blockIdx.x, mat = blockIdx.y, b = blockIdx.z;
  const float* __restrict__ P =
      (mat ? p2 : p1) + (size_t)b*NP*DD + (size_t)tile*TR*DD;
  const float* __restrict__ Qsrc = qt_ws + (size_t)b*DD*KSEL;
  const int t = threadIdx.x;
  const int w = t >> 6, l = t & 63;
  const int qg  = l & 3;         // query group (8 q)
  const int ds  = (l >> 2) & 3;  // d-slice (8 of 32 chunk dims)
  const int rgl = l >> 4;        // row group low (4 rows)
  const int rg  = w*4 + rgl;     // row group in [0,16)

  // ---- staging index precompute ----
  // P stage: sid = j*256+t in [0,512); LDS float off = sid*4 (linear).
  //   row r = sid>>3, quad s = sid&7; ds' = ((s>>1) ^ ((r>>2)&3))&3,
  //   dh' = (s&1) ^ ((r>>2)&1); global col = ds'*8 + dh'*4.
  int p_srcoff[2];
  #pragma unroll
  for (int j = 0; j < 2; ++j) {
    const int sid = j*256 + t;
    const int r = sid >> 3, s = sid & 7;
    const int dsd = ((s >> 1) ^ ((r >> 2) & 3)) & 3;
    const int dhd = (s & 1) ^ ((r >> 2) & 1);
    p_srcoff[j] = r*DD + dsd*8 + dhd*4;   // + c*DC at use
  }
  // Q stage: sid = t; LDS float off = t*4 (linear).
  //   dloc = t>>3, quad s = t&7; ds' = dloc>>3; qg' = ((s>>1)^ds')&3,
  //   qh' = (s&1)^(ds'&1); global col = qg'*8 + qh'*4.
  int q_srcoff;
  {
    const int dloc = t >> 3, s = t & 7;
    const int dsd = dloc >> 3;
    const int qgd = ((s >> 1) ^ dsd) & 3;
    const int qhd = (s & 1) ^ (dsd & 1);
    q_srcoff = dloc*KSEL + qgd*8 + qhd*4; // + c*DC*KSEL at use
  }

  // ---- read index precompute ----
  // P read (row r = w*16+rgl*4+i, d-half dh): float off = r*32 + Qp(dh)*4,
  //   Qp(dh) = ((ds^rgl)&3)*2 + (dh ^ (rgl&1)).
  const int pc2 = ((ds ^ rgl) & 3) * 2;
  const int pQ0 = pc2 + ((rgl & 1));        // dh=0
  const int pQ1 = pc2 + (1 ^ (rgl & 1));    // dh=1
  const int pRowBase = (w*16 + rgl*4) * DC; // +i*32, + quad*4
  // Q read (dloc = ds*8+dh*4+dd2, q-half qh): off = dloc*32 + Qq(qh)*4,
  //   Qq(qh) = ((qg^ds)&3)*2 + (qh ^ (ds&1)).
  const int qc2 = ((qg ^ ds) & 3) * 2;
  const int qQ0 = qc2 + ((ds & 1));         // qh=0 -> q = qg*8..+4
  const int qQ1 = qc2 + (1 ^ (ds & 1));     // qh=1 -> q = qg*8+4..+8
  const int qRowBase = ds*8*KSEL;           // +(dh*4+dd2)*32, + quad*4

  // ---- prologue: stage chunk 0 ----
  {
    float* pb = &Ps[0][0];
    gload_lds16(P + p_srcoff[0],           pb + t*4);
    gload_lds16(P + p_srcoff[1],           pb + (256 + t)*4);
    gload_lds16(Qsrc + q_srcoff,           &Qc[0][0] + t*4);
  }
  asm volatile("s_waitcnt vmcnt(0)" ::: "memory");
  __syncthreads();

  float acc[8][4];
  float ssq[4];
  #pragma unroll
  for (int jj = 0; jj < 8; ++jj)
    #pragma unroll
    for (int i = 0; i < 4; ++i) acc[jj][i] = 0.f;
  #pragma unroll
  for (int i = 0; i < 4; ++i) ssq[i] = 0.f;

  #pragma unroll 2
  for (int c = 0; c < NCH; ++c) {
    const int cur = c & 1;
    if (c + 1 < NCH) {
      float* pb = &Ps[cur ^ 1][0];
      const int gc = (c + 1) * DC;
      gload_lds16(P + (size_t)gc + p_srcoff[0], pb + t*4);
      gload_lds16(P + (size_t)gc + p_srcoff[1], pb + (256 + t)*4);
      gload_lds16(Qsrc + (size_t)gc*KSEL + q_srcoff, &Qc[cur ^ 1][0] + t*4);
    }
    const float* __restrict__ pb = &Ps[cur][0];
    const float* __restrict__ qb = &Qc[cur][0];
    #pragma unroll
    for (int dh = 0; dh < 2; ++dh) {
      const int pQ = dh ? pQ1 : pQ0;
      float4 p4[4];
      #pragma unroll
      for (int i = 0; i < 4; ++i)
        p4[i] = *(const float4*)&pb[pRowBase + i*DC + pQ*4];
      #pragma unroll
      for (int dd2 = 0; dd2 < 4; ++dd2) {
        const int drow = qRowBase + (dh*4 + dd2)*KSEL;
        const float4 q0 = *(const float4*)&qb[drow + qQ0*4];
        const float4 q1 = *(const float4*)&qb[drow + qQ1*4];
        #pragma unroll
        for (int i = 0; i < 4; ++i) {
          const float p = (dd2 == 0) ? p4[i].x : (dd2 == 1) ? p4[i].y
                         : (dd2 == 2) ? p4[i].z : p4[i].w;
          acc[0][i] += q0.x*p; acc[1][i] += q0.y*p;
          acc[2][i] += q0.z*p; acc[3][i] += q0.w*p;
          acc[4][i] += q1.x*p; acc[5][i] += q1.y*p;
          acc[6][i] += q1.z*p; acc[7][i] += q1.w*p;
          ssq[i] += p*p;
        }
      }
    }
    asm volatile("s_waitcnt vmcnt(0)" ::: "memory");
    __syncthreads();
  }

  // ---- reduce the 4-way d-split (ds = lane bits 2-3) by butterfly ----
  #pragma unroll
  for (int jj = 0; jj < 8; ++jj)
    #pragma unroll
    for (int i = 0; i < 4; ++i) {
      acc[jj][i] += __shfl_xor(acc[jj][i], 4, 64);
      acc[jj][i] += __shfl_xor(acc[jj][i], 8, 64);
    }
  #pragma unroll
  for (int i = 0; i < 4; ++i) {
    ssq[i] += __shfl_xor(ssq[i], 4, 64);
    ssq[i] += __shfl_xor(ssq[i], 8, 64);
  }

  float rinvp[4];
  #pragma unroll
  for (int i = 0; i < 4; ++i)
    rinvp[i] = 1.f / fmaxf(sqrtf(ssq[i]), 1e-12f);

  // ---- (max, argmax) epilogue; first-occurrence ties (ascending rows) ----
  float* redv = &Ps[0][0];            // [16][32]
  int*   redi = (int*)&Ps[0][512];    // [16][32]

  if (ds == 0) {
    #pragma unroll
    for (int jj = 0; jj < 8; ++jj) {
      const int q = qg*8 + jj;
      float best = -1e30f; int bi = 0;
      #pragma unroll
      for (int i = 0; i < 4; ++i) {
        const float s = acc[jj][i] * rinvp[i];
        if (s > best) { best = s; bi = rg*4 + i; }
      }
      redv[rg*32 + q] = best;
      redi[rg*32 + q] = bi;
    }
  }
  __syncthreads();
  if (t < 32) {
    const int q = t;
    float best = -1e30f; int bi = 0;
    #pragma unroll
    for (int g = 0; g < 16; ++g) {
      const float v = redv[g*32 + q];
      if (v > best) { best = v; bi = redi[g*32 + q]; }
    }
    const int o = ((b*2 + mat)*NT + tile)*KSEL + q;
    pmax_ws[o] = best;
    pidx_ws[o] = tile*TR + bi;
  }
}

// ---------------------------------------------------------------------------
// Kernel C: per (b,k) reduce tile partials, gather+normalize matched rows,
// fuse with weights, renormalize, write P_s.
// ---------------------------------------------------------------------------
__global__ __launch_bounds__(256) void fuse_kernel(
    const float* __restrict__ p1, const float* __restrict__ p2,
    const float* __restrict__ pmax_ws, const int* __restrict__ pidx_ws,
    float* __restrict__ outP) {
  const int blk = blockIdx.x;          // b*32 + k
  const int b = blk >> 5, k = blk & 31;
  const int t = threadIdx.x;

  float w1 = -1e30f, w2 = -1e30f; int i1 = 0, i2 = 0;
  for (int tl = 0; tl < NT; ++tl) {
    const int o1 = ((b*2 + 0)*NT + tl)*KSEL + k;
    const float v = pmax_ws[o1];
    if (v > w1) { w1 = v; i1 = pidx_ws[o1]; }
    const int o2 = ((b*2 + 1)*NT + tl)*KSEL + k;
    const float u = pmax_ws[o2];
    if (u > w2) { w2 = u; i2 = pidx_ws[o2]; }
  }

  const float* r1 = p1 + ((size_t)b*NP + i1)*DD;
  const float* r2 = p2 + ((size_t)b*NP + i2)*DD;
  float2 a  = *(const float2*)(r1 + 2*t);
  float2 c2 = *(const float2*)(r2 + 2*t);
  float s1 = a.x*a.x + a.y*a.y;
  float s2 = c2.x*c2.x + c2.y*c2.y;
  #pragma unroll
  for (int o = 1; o < 64; o <<= 1) {
    s1 += __shfl_xor(s1, o, 64);
    s2 += __shfl_xor(s2, o, 64);
  }
  __shared__ float lb[12];
  const int w = t >> 6, l = t & 63;
  if (l == 0) { lb[w] = s1; lb[4+w] = s2; }
  __syncthreads();
  s1 = lb[0]+lb[1]+lb[2]+lb[3];
  s2 = lb[4]+lb[5]+lb[6]+lb[7];
  const float rn1 = 1.f / fmaxf(sqrtf(s1), 1e-12f);
  const float rn2 = 1.f / fmaxf(sqrtf(s2), 1e-12f);

  const float invd = 1.f / (w1 + w2 + 1e-6f);
  const float fx = (w1*(a.x*rn1)  + w2*(c2.x*rn2)) * invd;
  const float fy = (w1*(a.y*rn1)  + w2*(c2.y*rn2)) * invd;

  float sf = fx*fx + fy*fy;
  #pragma unroll
  for (int o = 1; o < 64; o <<= 1) sf += __shfl_xor(sf, o, 64);
  if (l == 0) lb[8+w] = sf;
  __syncthreads();
  sf = lb[8]+lb[9]+lb[10]+lb[11];
  const float rf = 1.f / fmaxf(sqrtf(sf), 1e-12f);

  float2 o2; o2.x = fx*rf; o2.y = fy*rf;
  *(float2*)(outP + (size_t)blk*DD + 2*t) = o2;
}

extern "C" void kernel_launch(void* const* d_in, const int* in_sizes, int n_in,
                              void* d_out, int out_size, void* d_ws, size_t ws_size,
                              hipStream_t stream) {
  (void)in_sizes; (void)n_in; (void)out_size; (void)ws_size;
  const float* anchor = (const float*)d_in[0];
  const float* p1     = (const float*)d_in[1];
  const float* p2     = (const float*)d_in[2];
  const int*   idx_a  = (const int*)d_in[3];
  const int*   idx_p  = (const int*)d_in[4];

  float* out  = (float*)d_out;
  float* outA = out;                       // (B,K,D)
  float* outP = out + (size_t)BB*KSEL*DD;  // (B,K,D)

  float* ws   = (float*)d_ws;
  float* qt   = ws + QT_OFF;
  float* pmax = ws + PMAX_OFF;
  int*   pidx = (int*)(ws + PIDX_OFF);

  hipLaunchKernelGGL(prep_kernel, dim3(BB*KSEL), dim3(256), 0, stream,
                     anchor, idx_a, idx_p, outA, qt);
  hipLaunchKernelGGL(match_kernel, dim3(NT, 2, BB), dim3(256), 0, stream,
                     p1, p2, qt, pmax, pidx);
  hipLaunchKernelGGL(fuse_kernel, dim3(BB*KSEL), dim3(256), 0, stream,
                     p1, p2, pmax, pidx, outP);
}